// Round 17
// baseline (201.662 us; speedup 1.0000x reference)
//
#include <hip/hip_runtime.h>

// ============================ EVIDENCE LOG ============================
//  Facts: inputs fp32 time-major as shown; rows/cols int32; d_out FP32
//    (R11 sentinel); out=[out0|out1] each [Tp,n] flat; semantics = shown
//    jnp reference (absmax 0.0625 since R12). Sparse: gather rows[k],
//    scatter cols[k].
//  R12 512us (global-atomic RMW amp). R13 197us (CSR + gather fused).
//  R14 194us (single-WG CSR = serialization anti-pattern).
//  R15 149us (transpose-all; M transpose wasted 35MB).
//  R16 141.8us (C/D-only transpose, split sparse/final): all own kernels
//    <41us each; top-5 = harness 268MB ws-poison fills (~42us, fixed).
//    Residual ~65us of ours across 6 dispatches => per-dispatch overhead +
//    serialized CSR chain (memset->hist->scan->fill) dominates, not work.
//  THIS ROUND: kill the CSR. Block = 32c x 32i tile builds its own edge
//    list from cols[] (coalesced scan, deterministic 2-pass, LDS cap 3072
//    w/ correct direct-scan fallback), sparse into LDS [c][i] via LDS
//    float atomics, then cov+mob (native M) + coalesced stores.
//    2 dispatches total: transposeCD + mega.
// ======================================================================

#define BS     256
#define CTILE  32
#define ITILE  32
#define ECAP   3072   // expected ~320 edges/block (binomial tail ~0)
#define SCAN_TH 1024

// ---- dispatch 1: transpose C, D ([T,NC] -> [NC,T]) via LDS 64x64 tiles ----
__global__ void transposeCD(const float* __restrict__ C, const float* __restrict__ D,
                            float* __restrict__ Ct, float* __restrict__ Dt,
                            int T, int NC, int cT, int tT) {
    __shared__ float tile[64][65];
    int bid = blockIdx.x;
    int z  = bid / (cT * tT);
    int r  = bid - z * cT * tT;
    int ct = r / tT;
    int tt = r - ct * tT;
    const float* src = z ? D : C;
    float* dst = z ? Dt : Ct;
    int lx = threadIdx.x & 63, ly = threadIdx.x >> 6;   // 64 x 4
    int c0 = ct * 64, t0 = tt * 64;
    for (int rr = ly; rr < 64; rr += 4) {
        int t = t0 + rr, c = c0 + lx;
        if (t < T && c < NC) tile[rr][lx] = src[(size_t)t * NC + c];
    }
    __syncthreads();
    for (int rr = ly; rr < 64; rr += 4) {
        int c = c0 + rr, t = t0 + lx;
        if (c < NC && t < T) dst[(size_t)c * T + t] = tile[lx][rr];
    }
}

// ---- dispatch 2: mega kernel. One block per (32i x 32c) output tile. ----
__global__ __launch_bounds__(BS)
void mega(const float* __restrict__ Ct,  // [NC, T]
          const float* __restrict__ Dt,  // [NC, T]
          const float* __restrict__ M,   // [NMOB, T, NC] native
          const float* __restrict__ cov, // [NCOV, NC]
          const float* __restrict__ mu,  // [NMOB, 2]
          const float* __restrict__ nu,  // [NMOB, 2]
          const float* __restrict__ ups, // [NCOV]
          const float* __restrict__ zet, // [NCOV]
          const int*  __restrict__ rows,
          const int*  __restrict__ cols,
          const float* __restrict__ Bnz,
          const float* __restrict__ Anz,
          const float* __restrict__ Hnz,
          float* __restrict__ out0, float* __restrict__ out1,
          int T, int NC, int NMOB, int NCOV, int NNZ, int TPn, int cTiles) {
    __shared__ int   s_edge[ECAP];
    __shared__ float s_a0[CTILE][ITILE + 1];   // [c][i], pad -> stride 33
    __shared__ float s_a1[CTILE][ITILE + 1];
    __shared__ int   s_scan[BS];

    int bi = blockIdx.x / cTiles;
    int bc = blockIdx.x - bi * cTiles;
    int i0 = bi * ITILE, c0 = bc * CTILE;
    int tid = threadIdx.x;
    int cmax = NC - c0; if (cmax > CTILE) cmax = CTILE;

    // zero LDS accumulators
    for (int x = tid; x < CTILE * (ITILE + 1); x += BS) {
        ((float*)s_a0)[x] = 0.f;
        ((float*)s_a1)[x] = 0.f;
    }

    // ---- build block-local edge list from cols[] (deterministic 2-pass) ----
    int cnt = 0;
    for (int k = tid; k < NNZ; k += BS) {
        int cl = cols[k] - c0;
        if ((unsigned)cl < (unsigned)cmax) cnt++;
    }
    s_scan[tid] = cnt;
    __syncthreads();
    for (int off = 1; off < BS; off <<= 1) {           // Hillis-Steele
        int v = (tid >= off) ? s_scan[tid - off] : 0;
        __syncthreads();
        s_scan[tid] += v;
        __syncthreads();
    }
    int total = s_scan[BS - 1];
    int wpos = s_scan[tid] - cnt;                      // exclusive prefix
    if (total <= ECAP) {
        for (int k = tid; k < NNZ; k += BS) {
            int cl = cols[k] - c0;
            if ((unsigned)cl < (unsigned)cmax) s_edge[wpos++] = (k << 5) | cl;
        }
    }
    __syncthreads();

    // ---- phase A: sparse term, lanes along i (Ct/Dt coalesced) ----
    int li  = tid & 31;        // i lane
    int grp = tid >> 5;        // 0..7
    int iA  = i0 + li;
    int isafe = (iA < TPn) ? iA : (TPn - 1);   // isafe+1 <= TPn < T: safe
    if (total <= ECAP) {
        for (int e = grp; e < total; e += 8) {
            int pk = s_edge[e];
            int k = pk >> 5, cl = pk & 31;
            int g = rows[k];
            float Bv = Bnz[k], Av = Anz[k], Hv = Hnz[k];
            const float* cr = Ct + (size_t)g * T;
            const float* dr = Dt + (size_t)g * T;
            float cs = cr[isafe] + cr[isafe + 1];
            float ds = dr[isafe] + dr[isafe + 1];
            atomicAdd(&s_a0[cl][li], cs * Bv);
            atomicAdd(&s_a1[cl][li], cs * Hv + ds * Av);
        }
    } else {
        // overflow fallback (never expected): direct scan, still correct
        for (int k = grp; k < NNZ; k += 8) {
            int cl = cols[k] - c0;
            if ((unsigned)cl < (unsigned)cmax) {
                int g = rows[k];
                float Bv = Bnz[k], Av = Anz[k], Hv = Hnz[k];
                const float* cr = Ct + (size_t)g * T;
                const float* dr = Dt + (size_t)g * T;
                float cs = cr[isafe] + cr[isafe + 1];
                float ds = dr[isafe] + dr[isafe + 1];
                atomicAdd(&s_a0[cl][li], cs * Bv);
                atomicAdd(&s_a1[cl][li], cs * Hv + ds * Av);
            }
        }
    }
    __syncthreads();

    // ---- phase B: cov + mob (native-layout M, lanes along c) + store ----
    int lc = tid & 31;         // c lane
    int ri = tid >> 5;         // 0..7
    int c = c0 + lc;
    if (c >= NC) return;

    float cv0 = 0.f, cv1 = 0.f;
    for (int j = 0; j < NCOV; ++j) {
        float cv = cov[(size_t)j * NC + c];
        cv0 += cv * ups[j];
        cv1 += cv * zet[j];
    }
    for (int ii = ri; ii < ITILE; ii += 8) {
        int io = i0 + ii;
        if (io >= TPn) break;
        float a0 = s_a0[lc][ii] + cv0;    // stride-33 read: conflict-free
        float a1 = s_a1[lc][ii] + cv1;
        for (int k = 0; k < NMOB; ++k) {
            const float* mb = M + (size_t)k * T * NC;
            float m0 = mb[(size_t)io * NC + c];
            float m1 = mb[(size_t)(io + 1) * NC + c];
            a0 += m0 * mu[k * 2] + m1 * mu[k * 2 + 1];
            a1 += m0 * nu[k * 2] + m1 * nu[k * 2 + 1];
        }
        out0[(size_t)io * NC + c] = a0;
        out1[(size_t)io * NC + c] = a1;
    }
}

// ================= fallback path (P != 2): R13-proven CSR chain =========
__global__ void csr_hist(const int* __restrict__ cols, int* __restrict__ counts, int NNZ) {
    int k = blockIdx.x * blockDim.x + threadIdx.x;
    if (k < NNZ) atomicAdd(&counts[cols[k]], 1);
}
__global__ __launch_bounds__(SCAN_TH)
void csr_scan(const int* __restrict__ counts, int* __restrict__ offsets,
              int* __restrict__ cursor, int NC) {
    __shared__ int ssum[SCAN_TH];
    int t = threadIdx.x;
    int chunk = (NC + SCAN_TH - 1) / SCAN_TH;
    int beg = t * chunk, end = min(beg + chunk, NC);
    int local = 0;
    for (int j = beg; j < end; ++j) local += counts[j];
    ssum[t] = local;
    __syncthreads();
    for (int off = 1; off < SCAN_TH; off <<= 1) {
        int v = (t >= off) ? ssum[t - off] : 0;
        __syncthreads();
        ssum[t] += v;
        __syncthreads();
    }
    int run = ssum[t] - local;
    for (int j = beg; j < end; ++j) {
        offsets[j] = run;
        cursor[j]  = run;
        run += counts[j];
    }
    if (t == SCAN_TH - 1) offsets[NC] = ssum[SCAN_TH - 1];
}
__global__ void csr_fill(const int* __restrict__ rows, const int* __restrict__ cols,
                         const float* __restrict__ Bnz, const float* __restrict__ Anz,
                         const float* __restrict__ Hnz,
                         int* __restrict__ cursor, float4* __restrict__ edges, int NNZ) {
    int k = blockIdx.x * blockDim.x + threadIdx.x;
    if (k >= NNZ) return;
    int s = cols[k];
    int pos = atomicAdd(&cursor[s], 1);
    edges[pos] = make_float4(__int_as_float(rows[k]), Bnz[k], Anz[k], Hnz[k]);
}
__global__ void fused_generic(const float* __restrict__ C, const float* __restrict__ D,
                              const float* __restrict__ M, const float* __restrict__ cov,
                              const float* __restrict__ mu, const float* __restrict__ nu,
                              const float* __restrict__ ups, const float* __restrict__ zet,
                              const int* __restrict__ offsets, const float4* __restrict__ edges,
                              float* __restrict__ out0, float* __restrict__ out1,
                              int T, int NC, int NMOB, int NCOV, int P, int TPn) {
    int idx = blockIdx.x * blockDim.x + threadIdx.x;
    if (idx >= TPn * NC) return;
    int i = idx / NC;
    int c = idx - i * NC;
    float acc0 = 0.f, acc1 = 0.f;
    for (int k = 0; k < NMOB; ++k)
        for (int tau = 0; tau < P; ++tau) {
            float m = M[((size_t)k * T + i + tau) * NC + c];
            acc0 += m * mu[k * P + tau];
            acc1 += m * nu[k * P + tau];
        }
    for (int j = 0; j < NCOV; ++j) {
        float cv = cov[(size_t)j * NC + c];
        acc0 += cv * ups[j];
        acc1 += cv * zet[j];
    }
    int e0 = offsets[c], e1 = offsets[c + 1];
    for (int e = e0; e < e1; ++e) {
        float4 E = edges[e];
        int g = __float_as_int(E.x);
        float cs = 0.f, ds = 0.f;
        for (int tau = 0; tau < P; ++tau) {
            cs += C[(size_t)(i + tau) * NC + g];
            ds += D[(size_t)(i + tau) * NC + g];
        }
        acc0 += cs * E.y;
        acc1 += cs * E.w + ds * E.z;
    }
    out0[idx] = acc0;
    out1[idx] = acc1;
}

extern "C" void kernel_launch(void* const* d_in, const int* in_sizes, int n_in,
                              void* d_out, int out_size, void* d_ws, size_t ws_size,
                              hipStream_t stream) {
    const float* C    = (const float*)d_in[0];
    const float* D    = (const float*)d_in[1];
    const float* M    = (const float*)d_in[2];
    const float* cov  = (const float*)d_in[3];
    const float* Bnz  = (const float*)d_in[4];
    const float* Anz  = (const float*)d_in[5];
    const float* Hnz  = (const float*)d_in[6];
    const float* mu   = (const float*)d_in[7];
    const float* nu   = (const float*)d_in[8];
    const float* ups  = (const float*)d_in[9];
    const float* zet  = (const float*)d_in[10];
    const int*  rows  = (const int*)d_in[11];
    const int*  cols  = (const int*)d_in[12];

    int NCOV = in_sizes[9];                 // 10
    int NC   = in_sizes[3] / NCOV;          // 3144
    int T    = in_sizes[0] / NC;            // 156
    int NMOB = in_sizes[2] / in_sizes[0];   // 6
    int P    = in_sizes[7] / NMOB;          // 2
    int NNZ  = in_sizes[11];                // 31440
    int TPn  = T - P;                       // 154

    float* out0 = (float*)d_out;            // fp32
    float* out1 = out0 + (size_t)TPn * NC;

    // ws carve-up: edges | offsets | counts | cursor | Ct | Dt
    float4* edges   = (float4*)d_ws;
    int*    offsets = (int*)(edges + NNZ);
    int*    counts  = offsets + (NC + 1);
    int*    cursor  = counts + NC;
    float*  Ct      = (float*)(cursor + NC);
    float*  Dt      = Ct + (size_t)NC * T;
    size_t  need    = (size_t)((char*)(Dt + (size_t)NC * T) - (char*)d_ws);

    if (P == 2 && ws_size >= need && NNZ < (1 << 26)) {
        int cT = (NC + 63) / 64, tT = (T + 63) / 64;
        transposeCD<<<2 * cT * tT, BS, 0, stream>>>(C, D, Ct, Dt, T, NC, cT, tT);

        int iTiles = (TPn + ITILE - 1) / ITILE;   // 5
        int cTiles = (NC + CTILE - 1) / CTILE;    // 99
        mega<<<iTiles * cTiles, BS, 0, stream>>>(
            Ct, Dt, M, cov, mu, nu, ups, zet, rows, cols, Bnz, Anz, Hnz,
            out0, out1, T, NC, NMOB, NCOV, NNZ, TPn, cTiles);
    } else {
        hipMemsetAsync(counts, 0, (size_t)NC * sizeof(int), stream);
        csr_hist<<<(NNZ + BS - 1) / BS, BS, 0, stream>>>(cols, counts, NNZ);
        csr_scan<<<1, SCAN_TH, 0, stream>>>(counts, offsets, cursor, NC);
        csr_fill<<<(NNZ + BS - 1) / BS, BS, 0, stream>>>(
            rows, cols, Bnz, Anz, Hnz, cursor, edges, NNZ);
        int n = TPn * NC;
        fused_generic<<<(n + BS - 1) / BS, BS, 0, stream>>>(
            C, D, M, cov, mu, nu, ups, zet, offsets, edges,
            out0, out1, T, NC, NMOB, NCOV, P, TPn);
    }
}